// Round 1
// baseline (772.702 us; speedup 1.0000x reference)
//
#include <hip/hip_runtime.h>

// Spatial correlation sampler: out[b,ph,pw,y,x] = sum_c in1[b,c,y,x]*in2[b,c,y+ph-10,x+pw-10]
// B=4 C=256 H=W=128 P=21 D=10, zero padding outside in2 bounds.

#define BDIM 4
#define CDIM 256
#define HDIM 128
#define WDIM 128
#define PP   21
#define DD   10
#define KC   8      // channels per LDS chunk
#define NSLOT 8     // ph slots per pass (3 passes cover 21)
#define S2W  152    // in2 LDS row width: x in [-12, 139] (aligned float4 window)

__global__ __launch_bounds__(256, 2)
void corr_kernel(const float* __restrict__ in1,
                 const float* __restrict__ in2,
                 float* __restrict__ out) {
    __shared__ float s1[KC][WDIM];          // 4 KB: in1 row chunk
    __shared__ float s2[NSLOT][KC][S2W];    // 38.9 KB: in2 rows, col = x + 12

    const int tid  = threadIdx.x;
    const int xg   = tid & 31;   // x-group: pixels xg*4 .. xg*4+3
    const int slot = tid >> 5;   // ph slot 0..7
    const int bid  = blockIdx.x; // b*128 + y
    const int b    = bid >> 7;
    const int y    = bid & 127;

    const float* in1row = in1 + (((size_t)b * CDIM) * HDIM + y) * WDIM;

    for (int pass = 0; pass < 3; ++pass) {
        const int ph = slot + NSLOT * pass;   // may be >= 21 in pass 2

        float acc[PP][4];
        #pragma unroll
        for (int pw = 0; pw < PP; ++pw)
            #pragma unroll
            for (int px = 0; px < 4; ++px) acc[pw][px] = 0.0f;

        for (int c0 = 0; c0 < CDIM; c0 += KC) {
            __syncthreads();  // protect LDS from previous chunk's readers

            // ---- stage in1: KC x 128 floats, one float4 per thread ----
            {
                const int c = tid >> 5;
                const int x = (tid & 31) * 4;
                const float4 v = *(const float4*)(in1row + (size_t)(c0 + c) * HDIM * WDIM + x);
                *(float4*)&s1[c][x] = v;
            }
            // ---- stage in2: NSLOT x KC x 38 float4 (zero-filled halo) ----
            #pragma unroll
            for (int i = 0; i < 10; ++i) {
                const int idx = tid + 256 * i;
                if (idx < NSLOT * KC * 38) {
                    const int col4 = idx % 38;
                    const int rc   = idx / 38;
                    const int c    = rc & (KC - 1);
                    const int s    = rc >> 3;
                    const int u    = y + s + NSLOT * pass - DD;   // in2 row
                    const int x0   = col4 * 4 - 12;               // global x of first elem
                    float4 v = make_float4(0.f, 0.f, 0.f, 0.f);
                    if (u >= 0 && u < HDIM && x0 >= 0 && x0 + 3 < WDIM) {
                        v = *(const float4*)(in2 + (((size_t)(b * CDIM + c0 + c)) * HDIM + u) * WDIM + x0);
                    }
                    *(float4*)&s2[s][c][col4 * 4] = v;
                }
            }
            __syncthreads();

            // ---- compute: 4 px x 21 pw x KC channels ----
            if (ph < PP) {
                #pragma unroll
                for (int c = 0; c < KC; ++c) {
                    float a[4];
                    *(float4*)a = *(const float4*)&s1[c][xg * 4];
                    float w[28];
                    #pragma unroll
                    for (int j = 0; j < 7; ++j)
                        *(float4*)&w[4 * j] = *(const float4*)&s2[slot][c][xg * 4 + 4 * j];
                    // local col of in2 for (px,pw): x + pw - 10 + 12 - xg*4 = px + pw + 2
                    #pragma unroll
                    for (int pw = 0; pw < PP; ++pw)
                        #pragma unroll
                        for (int px = 0; px < 4; ++px)
                            acc[pw][px] = fmaf(a[px], w[px + pw + 2], acc[pw][px]);
                }
            }
        }

        if (ph < PP) {
            #pragma unroll
            for (int pw = 0; pw < PP; ++pw) {
                const size_t o = ((((size_t)b * PP + ph) * PP + pw) * HDIM + y) * WDIM + xg * 4;
                float4 v;
                v.x = acc[pw][0]; v.y = acc[pw][1]; v.z = acc[pw][2]; v.w = acc[pw][3];
                *(float4*)(out + o) = v;
            }
        }
    }
}

extern "C" void kernel_launch(void* const* d_in, const int* in_sizes, int n_in,
                              void* d_out, int out_size, void* d_ws, size_t ws_size,
                              hipStream_t stream) {
    const float* in1 = (const float*)d_in[0];
    const float* in2 = (const float*)d_in[1];
    float* out = (float*)d_out;
    // grid: one block per (b, y) image row
    corr_kernel<<<BDIM * HDIM, 256, 0, stream>>>(in1, in2, out);
}

// Round 3
// 297.487 us; speedup vs baseline: 2.5974x; 2.5974x over previous
//
#include <hip/hip_runtime.h>

#define BDIM 4
#define CDIM 256
#define HDIM 128
#define WDIM 128
#define PP   21
#define DD   10
#define HW   (HDIM*WDIM)

typedef __attribute__((ext_vector_type(8))) short short8;
typedef __attribute__((ext_vector_type(4))) float f32x4;

__device__ __forceinline__ unsigned short f2bf(float f) {
    union { float f; unsigned u; } v; v.f = f;
    unsigned u = v.u;
    return (unsigned short)((u + 0x7FFFu + ((u >> 16) & 1u)) >> 16);  // RNE
}

// ---------------- pre-pass: fp32 [b][c][p] -> bf16 [b][p][c] ----------------
__global__ __launch_bounds__(256)
void transpose_bf16_kernel(const float* __restrict__ in1,
                           const float* __restrict__ in2,
                           unsigned short* __restrict__ out1,
                           unsigned short* __restrict__ out2) {
    __shared__ unsigned short tile[64 * 64];   // [c_local][p_local], row 128B
    const int bid = blockIdx.x;
    const float* src;
    unsigned short* dst;
    const int t4 = bid & 4095;
    if (bid >> 12) { src = in2; dst = out2; } else { src = in1; dst = out1; }
    const int b   = t4 >> 10;
    const int rem = t4 & 1023;
    const int c0  = (rem >> 8) * 64;
    const int p0  = (rem & 255) * 64;
    const int t = threadIdx.x;

    // phase 1: coalesced fp32 read, cvt, LDS write [c][p]
    {
        const int c_l = t >> 2, pq = t & 3;
        const float* s = src + ((size_t)(b * CDIM + c0 + c_l)) * HW + p0 + pq * 16;
        #pragma unroll
        for (int i = 0; i < 4; ++i) {
            float4 v = *(const float4*)(s + i * 4);
            ushort4 w;
            w.x = f2bf(v.x); w.y = f2bf(v.y); w.z = f2bf(v.z); w.w = f2bf(v.w);
            *(ushort4*)&tile[c_l * 64 + pq * 16 + i * 4] = w;
        }
    }
    __syncthreads();
    // phase 2: read columns (2 lanes/bank = free), pack, store [p][c]
    {
        const int p_l = t & 63, cg = t >> 6;
        #pragma unroll
        for (int i = 0; i < 2; ++i) {
            const int cb = cg * 8 + i * 32;
            unsigned short vals[8];
            #pragma unroll
            for (int j = 0; j < 8; ++j) vals[j] = tile[(cb + j) * 64 + p_l];
            *(short8*)(dst + ((size_t)(b * HW + p0 + p_l)) * CDIM + c0 + cb) = *(short8*)vals;
        }
    }
}

// ---------------- main: banded MFMA correlation ----------------
#define SW 160                                   // in2 s-window rows (s in [-16,144))
#define LDS_IN2_BYTES (SW * CDIM * 2)            // 81920
#define LDS_OUT_OFF   LDS_IN2_BYTES
#define LDS_TOTAL     (LDS_IN2_BYTES + PP * WDIM * 4)   // 92672

__global__ __launch_bounds__(512, 1)
void corr_mfma_kernel(const unsigned short* __restrict__ in1t,
                      const unsigned short* __restrict__ in2t,
                      float* __restrict__ out) {
    extern __shared__ char lds[];
    float* souts = (float*)(lds + LDS_OUT_OFF);  // [21][128] band bounce

    const int tid  = threadIdx.x;
    const int lane = tid & 63;
    const int w    = tid >> 6;    // wave 0..7 -> x-tile
    const int x0   = w * 16;
    const int col  = lane & 15;
    const int g    = lane >> 4;

    // XCD-bijective swizzle: 512 blocks, 8 XCDs, each XCD walks 64 consecutive (b,y)
    const int bid = blockIdx.x;
    const int logical = (bid & 7) * 64 + (bid >> 3);
    const int b = logical >> 7;
    const int y = logical & 127;

    // in1 B-fragments for this wave's x-tile, all K=256: resident across ph loop.
    // frag layout: n = lane&15 (x), k = (lane>>4)*8 + j  (consistent k-map with A)
    short8 bfr[8];
    {
        const unsigned short* p1 =
            in1t + ((size_t)((b * HDIM + y) * WDIM + x0 + col)) * CDIM + g * 8;
        #pragma unroll
        for (int k = 0; k < 8; ++k) bfr[k] = *(const short8*)(p1 + k * 32);
    }

    const int ph_start = (DD - y) > 0 ? (DD - y) : 0;          // first valid u
    const int ph_end   = (HDIM + DD - y) < PP ? (HDIM + DD - y) : PP;

    const unsigned short* in2b = in2t + (size_t)b * HW * CDIM;
    short8 sreg[10];

    auto PRELOAD = [&](int ph) {
        const int u = y + ph - DD;
        #pragma unroll
        for (int i = 0; i < 10; ++i) {
            const int idx = tid + i * 512;
            const int row = idx >> 5;          // lds row = s + 16
            const int s   = row - 16;
            const int c0  = (idx & 31) * 8;
            short8 v = {0, 0, 0, 0, 0, 0, 0, 0};
            if (s >= 0 && s < WDIM)
                v = *(const short8*)(in2b + ((size_t)(u * WDIM + s)) * CDIM + c0);
            sreg[i] = v;
        }
    };

    PRELOAD(ph_start);

    for (int ph = 0; ph < PP; ++ph) {
        const int u = y + ph - DD;
        const bool valid = (u >= 0) && (u < HDIM);   // block-uniform
        float* outp = out + (((size_t)(b * PP + ph)) * PP) * HW + (size_t)y * WDIM;
        if (valid) {
            // write staged row into swizzled LDS [row][c], byte ^= (row&7)<<4
            #pragma unroll
            for (int i = 0; i < 10; ++i) {
                const int idx  = tid + i * 512;
                const int row  = idx >> 5;
                const int dstb = (idx * 16) ^ ((row & 7) << 4);
                *(short8*)(lds + dstb) = sreg[i];
            }
            __syncthreads();
            if (ph + 1 < ph_end) PRELOAD(ph + 1);   // hide HBM latency under MFMA

            // 3 s-tiles at s_base = x0-16+st*16 ; A: m = lane&15 (s), k = g*8+j
            #pragma unroll
            for (int st = 0; st < 3; ++st) {
                f32x4 acc = {0.f, 0.f, 0.f, 0.f};
                const int srow = x0 + st * 16 + col;     // = s + 16
                const int base = srow * 512 + g * 16;
                const int swz  = (srow & 7) << 4;
                #pragma unroll
                for (int k = 0; k < 8; ++k) {
                    const short8 afr = *(const short8*)(lds + ((base + k * 64) ^ swz));
                    acc = __builtin_amdgcn_mfma_f32_16x16x32_bf16(afr, bfr[k], acc, 0, 0, 0);
                }
                // band extract: D row m=g*4+r -> s, D col n=col -> x ; pw = s-x+10
                #pragma unroll
                for (int r = 0; r < 4; ++r) {
                    const int pw = st * 16 + g * 4 + r - col - 6;
                    if (pw >= 0 && pw < PP)
                        souts[pw * WDIM + x0 + col] = acc[r];
                }
            }
            __syncthreads();
            // coalesced store of [21][128] band
            #pragma unroll
            for (int it = 0; it < 2; ++it) {
                const int idx = tid + it * 512;
                if (idx < PP * 32) {
                    const int pw = idx >> 5;
                    const int x4 = (idx & 31) * 4;
                    *(float4*)(outp + (size_t)pw * HW + x4) =
                        *(const float4*)&souts[pw * WDIM + x4];
                }
            }
        } else {
            const float4 z = make_float4(0.f, 0.f, 0.f, 0.f);
            #pragma unroll
            for (int it = 0; it < 2; ++it) {
                const int idx = tid + it * 512;
                if (idx < PP * 32) {
                    const int pw = idx >> 5;
                    const int x4 = (idx & 31) * 4;
                    *(float4*)(outp + (size_t)pw * HW + x4) = z;
                }
            }
        }
    }
}

// ---------------- fallback (round-0 fp32 kernel, known-correct) ----------------
#define KC   8
#define NSLOT 8
#define S2W  152

__global__ __launch_bounds__(256, 2)
void corr_kernel(const float* __restrict__ in1,
                 const float* __restrict__ in2,
                 float* __restrict__ out) {
    __shared__ float s1[KC][WDIM];
    __shared__ float s2[NSLOT][KC][S2W];
    const int tid  = threadIdx.x;
    const int xg   = tid & 31;
    const int slot = tid >> 5;
    const int bid  = blockIdx.x;
    const int b    = bid >> 7;
    const int y    = bid & 127;
    const float* in1row = in1 + (((size_t)b * CDIM) * HDIM + y) * WDIM;
    for (int pass = 0; pass < 3; ++pass) {
        const int ph = slot + NSLOT * pass;
        float acc[PP][4];
        #pragma unroll
        for (int pw = 0; pw < PP; ++pw)
            #pragma unroll
            for (int px = 0; px < 4; ++px) acc[pw][px] = 0.0f;
        for (int c0 = 0; c0 < CDIM; c0 += KC) {
            __syncthreads();
            {
                const int c = tid >> 5;
                const int x = (tid & 31) * 4;
                const float4 v = *(const float4*)(in1row + (size_t)(c0 + c) * HW + x);
                *(float4*)&s1[c][x] = v;
            }
            #pragma unroll
            for (int i = 0; i < 10; ++i) {
                const int idx = tid + 256 * i;
                if (idx < NSLOT * KC * 38) {
                    const int col4 = idx % 38;
                    const int rc   = idx / 38;
                    const int c    = rc & (KC - 1);
                    const int s    = rc >> 3;
                    const int uu   = y + s + NSLOT * pass - DD;
                    const int x0   = col4 * 4 - 12;
                    float4 v = make_float4(0.f, 0.f, 0.f, 0.f);
                    if (uu >= 0 && uu < HDIM && x0 >= 0 && x0 + 3 < WDIM)
                        v = *(const float4*)(in2 + (((size_t)(b * CDIM + c0 + c)) * HDIM + uu) * WDIM + x0);
                    *(float4*)&s2[s][c][col4 * 4] = v;
                }
            }
            __syncthreads();
            if (ph < PP) {
                #pragma unroll
                for (int c = 0; c < KC; ++c) {
                    float a[4];
                    *(float4*)a = *(const float4*)&s1[c][xg * 4];
                    float wv[28];
                    #pragma unroll
                    for (int j = 0; j < 7; ++j)
                        *(float4*)&wv[4 * j] = *(const float4*)&s2[slot][c][xg * 4 + 4 * j];
                    #pragma unroll
                    for (int pw = 0; pw < PP; ++pw)
                        #pragma unroll
                        for (int px = 0; px < 4; ++px)
                            acc[pw][px] = fmaf(a[px], wv[px + pw + 2], acc[pw][px]);
                }
            }
        }
        if (ph < PP) {
            #pragma unroll
            for (int pw = 0; pw < PP; ++pw) {
                const size_t o = ((((size_t)b * PP + ph) * PP + pw) * HDIM + y) * WDIM + xg * 4;
                float4 v;
                v.x = acc[pw][0]; v.y = acc[pw][1]; v.z = acc[pw][2]; v.w = acc[pw][3];
                *(float4*)(out + o) = v;
            }
        }
    }
}

extern "C" void kernel_launch(void* const* d_in, const int* in_sizes, int n_in,
                              void* d_out, int out_size, void* d_ws, size_t ws_size,
                              hipStream_t stream) {
    const float* in1 = (const float*)d_in[0];
    const float* in2 = (const float*)d_in[1];
    float* out = (float*)d_out;

    const size_t elems = (size_t)BDIM * HW * CDIM;           // per input
    const size_t need  = 2 * elems * sizeof(unsigned short); // 64 MB
    if (ws_size >= need) {
        unsigned short* t1 = (unsigned short*)d_ws;
        unsigned short* t2 = t1 + elems;
        transpose_bf16_kernel<<<2 * BDIM * 4 * 256, 256, 0, stream>>>(in1, in2, t1, t2);
        hipFuncSetAttribute((const void*)corr_mfma_kernel,
                            hipFuncAttributeMaxDynamicSharedMemorySize, LDS_TOTAL);
        corr_mfma_kernel<<<BDIM * HDIM, 512, LDS_TOTAL, stream>>>(t1, t2, out);
    } else {
        corr_kernel<<<BDIM * HDIM, 256, 0, stream>>>(in1, in2, out);
    }
}

// Round 5
// 294.242 us; speedup vs baseline: 2.6261x; 1.0110x over previous
//
#include <hip/hip_runtime.h>

#define BDIM 4
#define CDIM 256
#define HDIM 128
#define WDIM 128
#define PP   21
#define DD   10
#define HW   (HDIM*WDIM)

typedef __attribute__((ext_vector_type(8))) short short8;
typedef __attribute__((ext_vector_type(4))) float f32x4;

__device__ __forceinline__ unsigned short f2bf(float f) {
    union { float f; unsigned u; } v; v.f = f;
    unsigned u = v.u;
    return (unsigned short)((u + 0x7FFFu + ((u >> 16) & 1u)) >> 16);  // RNE
}

// ---------------- pre-pass: fp32 [b][c][p] -> bf16 [b][p][c] ----------------
// 64(c) x 64(p) fp32 tile in LDS, column XOR-swizzled by (c & 28) so that
// phase-1 float4 writes stay 16B-aligned & at the b128 bank floor and
// phase-2 per-channel scalar reads are 2-way (free). Phase-2 lane map:
// 8 lanes cover 8 consecutive channels x 16B = 128B contiguous per p-row ->
// fully-coalesced full-granule global writes.
__global__ __launch_bounds__(256)
void transpose_bf16_kernel(const float* __restrict__ in1,
                           const float* __restrict__ in2,
                           unsigned short* __restrict__ out1,
                           unsigned short* __restrict__ out2) {
    __shared__ float tile[64 * 64];
    const int bid = blockIdx.x;
    const float* src;
    unsigned short* dst;
    const int t4 = bid & 4095;
    if (bid >> 12) { src = in2; dst = out2; } else { src = in1; dst = out1; }
    const int b   = t4 >> 10;
    const int rem = t4 & 1023;
    const int c0  = (rem >> 8) * 64;
    const int p0  = (rem & 255) * 64;
    const int t   = threadIdx.x;

    // phase 1: coalesced fp32 read, swizzled LDS write [c][p ^ (c&28)]
    {
        const int c_l = t >> 2, pq = t & 3;
        const int swz = c_l & 28;
        const float* s = src + ((size_t)(b * CDIM + c0 + c_l)) * HW + p0 + pq * 16;
        #pragma unroll
        for (int i = 0; i < 4; ++i) {
            const float4 v = *(const float4*)(s + i * 4);
            *(float4*)&tile[c_l * 64 + ((pq * 16 + i * 4) ^ swz)] = v;
        }
    }
    __syncthreads();
    // phase 2: gather 8 consecutive channels per lane, cvt, coalesced store
    #pragma unroll
    for (int it = 0; it < 2; ++it) {
        const int idx = t + it * 256;
        const int pr  = idx >> 3;          // p within tile (0..63)
        const int cl8 = (idx & 7) * 8;     // first channel of this lane's 8
        unsigned short vals[8];
        #pragma unroll
        for (int j = 0; j < 8; ++j) {
            const int c = cl8 + j;
            vals[j] = f2bf(tile[c * 64 + (pr ^ (c & 28))]);
        }
        *(short8*)(dst + ((size_t)(b * HW + p0 + pr)) * CDIM + c0 + cl8) =
            *(short8*)vals;
    }
}

// ---------------- main: banded MFMA correlation ----------------
#define SW 160                                   // in2 s-window rows (s in [-16,144))
#define LDS_IN2_BYTES (SW * CDIM * 2)            // 81920
#define LDS_OUT_OFF   LDS_IN2_BYTES
#define LDS_TOTAL     (LDS_IN2_BYTES + PP * WDIM * 4)   // 92672

__global__ __launch_bounds__(512, 1)
void corr_mfma_kernel(const unsigned short* __restrict__ in1t,
                      const unsigned short* __restrict__ in2t,
                      float* __restrict__ out) {
    extern __shared__ char lds[];
    float* souts = (float*)(lds + LDS_OUT_OFF);  // [21][128] band bounce

    const int tid  = threadIdx.x;
    const int lane = tid & 63;
    const int w    = tid >> 6;    // wave 0..7 -> x-tile
    const int x0   = w * 16;
    const int col  = lane & 15;
    const int g    = lane >> 4;

    // XCD-bijective swizzle: 512 blocks, 8 XCDs, each XCD walks 64 consecutive (b,y)
    const int bid = blockIdx.x;
    const int logical = (bid & 7) * 64 + (bid >> 3);
    const int b = logical >> 7;
    const int y = logical & 127;

    // in1 B-fragments for this wave's x-tile, all K=256: resident across ph loop.
    // frag layout: n = lane&15 (x), k = (lane>>4)*8 + j  (consistent k-map with A)
    short8 bfr[8];
    {
        const unsigned short* p1 =
            in1t + ((size_t)((b * HDIM + y) * WDIM + x0 + col)) * CDIM + g * 8;
        #pragma unroll
        for (int k = 0; k < 8; ++k) bfr[k] = *(const short8*)(p1 + k * 32);
    }

    const int ph_start = (DD - y) > 0 ? (DD - y) : 0;          // first valid u
    const int ph_end   = (HDIM + DD - y) < PP ? (HDIM + DD - y) : PP;

    const unsigned short* in2b = in2t + (size_t)b * HW * CDIM;
    short8 sreg[10];

    auto PRELOAD = [&](int ph) {
        const int u = y + ph - DD;
        #pragma unroll
        for (int i = 0; i < 10; ++i) {
            const int idx = tid + i * 512;
            const int row = idx >> 5;          // lds row = s + 16
            const int s   = row - 16;
            const int c0  = (idx & 31) * 8;
            short8 v = {0, 0, 0, 0, 0, 0, 0, 0};
            if (s >= 0 && s < WDIM)
                v = *(const short8*)(in2b + ((size_t)(u * WDIM + s)) * CDIM + c0);
            sreg[i] = v;
        }
    };

    PRELOAD(ph_start);

    for (int ph = 0; ph < PP; ++ph) {
        const int u = y + ph - DD;
        const bool valid = (u >= 0) && (u < HDIM);   // block-uniform
        float* outp = out + (((size_t)(b * PP + ph)) * PP) * HW + (size_t)y * WDIM;
        if (valid) {
            // write staged row into swizzled LDS [row][c], byte ^= (row&7)<<4
            #pragma unroll
            for (int i = 0; i < 10; ++i) {
                const int idx  = tid + i * 512;
                const int row  = idx >> 5;
                const int dstb = (idx * 16) ^ ((row & 7) << 4);
                *(short8*)(lds + dstb) = sreg[i];
            }
            __syncthreads();
            if (ph + 1 < ph_end) PRELOAD(ph + 1);   // hide HBM latency under MFMA

            // 3 s-tiles at s_base = x0-16+st*16 ; A: m = lane&15 (s), k = g*8+j
            #pragma unroll
            for (int st = 0; st < 3; ++st) {
                f32x4 acc = {0.f, 0.f, 0.f, 0.f};
                const int s_lo = x0 + st * 16 - 16;           // actual s of row 0
                if (s_lo < WDIM && s_lo + 16 > 0) {           // skip all-zero tiles
                    const int srow = x0 + st * 16 + col;      // = s + 16
                    const int base = srow * 512 + g * 16;
                    const int swz  = (srow & 7) << 4;
                    #pragma unroll
                    for (int k = 0; k < 8; ++k) {
                        const short8 afr = *(const short8*)(lds + ((base + k * 64) ^ swz));
                        acc = __builtin_amdgcn_mfma_f32_16x16x32_bf16(afr, bfr[k], acc, 0, 0, 0);
                    }
                }
                // band extract: D row m=g*4+r -> s, D col n=col -> x ; pw = s-x+10
                #pragma unroll
                for (int r = 0; r < 4; ++r) {
                    const int pw = st * 16 + g * 4 + r - col - 6;
                    if (pw >= 0 && pw < PP)
                        souts[pw * WDIM + x0 + col] = acc[r];
                }
            }
            __syncthreads();
            // coalesced store of [21][128] band
            #pragma unroll
            for (int it = 0; it < 2; ++it) {
                const int idx = tid + it * 512;
                if (idx < PP * 32) {
                    const int pw = idx >> 5;
                    const int x4 = (idx & 31) * 4;
                    *(float4*)(outp + (size_t)pw * HW + x4) =
                        *(const float4*)&souts[pw * WDIM + x4];
                }
            }
        } else {
            const float4 z = make_float4(0.f, 0.f, 0.f, 0.f);
            #pragma unroll
            for (int it = 0; it < 2; ++it) {
                const int idx = tid + it * 512;
                if (idx < PP * 32) {
                    const int pw = idx >> 5;
                    const int x4 = (idx & 31) * 4;
                    *(float4*)(outp + (size_t)pw * HW + x4) = z;
                }
            }
        }
    }
}

// ---------------- fallback (round-0 fp32 kernel, known-correct) ----------------
#define KC   8
#define NSLOT 8
#define S2W  152

__global__ __launch_bounds__(256, 2)
void corr_kernel(const float* __restrict__ in1,
                 const float* __restrict__ in2,
                 float* __restrict__ out) {
    __shared__ float s1[KC][WDIM];
    __shared__ float s2[NSLOT][KC][S2W];
    const int tid  = threadIdx.x;
    const int xg   = tid & 31;
    const int slot = tid >> 5;
    const int bid  = blockIdx.x;
    const int b    = bid >> 7;
    const int y    = bid & 127;
    const float* in1row = in1 + (((size_t)b * CDIM) * HDIM + y) * WDIM;
    for (int pass = 0; pass < 3; ++pass) {
        const int ph = slot + NSLOT * pass;
        float acc[PP][4];
        #pragma unroll
        for (int pw = 0; pw < PP; ++pw)
            #pragma unroll
            for (int px = 0; px < 4; ++px) acc[pw][px] = 0.0f;
        for (int c0 = 0; c0 < CDIM; c0 += KC) {
            __syncthreads();
            {
                const int c = tid >> 5;
                const int x = (tid & 31) * 4;
                const float4 v = *(const float4*)(in1row + (size_t)(c0 + c) * HW + x);
                *(float4*)&s1[c][x] = v;
            }
            #pragma unroll
            for (int i = 0; i < 10; ++i) {
                const int idx = tid + 256 * i;
                if (idx < NSLOT * KC * 38) {
                    const int col4 = idx % 38;
                    const int rc   = idx / 38;
                    const int c    = rc & (KC - 1);
                    const int s    = rc >> 3;
                    const int uu   = y + s + NSLOT * pass - DD;
                    const int x0   = col4 * 4 - 12;
                    float4 v = make_float4(0.f, 0.f, 0.f, 0.f);
                    if (uu >= 0 && uu < HDIM && x0 >= 0 && x0 + 3 < WDIM)
                        v = *(const float4*)(in2 + (((size_t)(b * CDIM + c0 + c)) * HDIM + uu) * WDIM + x0);
                    *(float4*)&s2[s][c][col4 * 4] = v;
                }
            }
            __syncthreads();
            if (ph < PP) {
                #pragma unroll
                for (int c = 0; c < KC; ++c) {
                    float a[4];
                    *(float4*)a = *(const float4*)&s1[c][xg * 4];
                    float wv[28];
                    #pragma unroll
                    for (int j = 0; j < 7; ++j)
                        *(float4*)&wv[4 * j] = *(const float4*)&s2[slot][c][xg * 4 + 4 * j];
                    #pragma unroll
                    for (int pw = 0; pw < PP; ++pw)
                        #pragma unroll
                        for (int px = 0; px < 4; ++px)
                            acc[pw][px] = fmaf(a[px], wv[px + pw + 2], acc[pw][px]);
                }
            }
        }
        if (ph < PP) {
            #pragma unroll
            for (int pw = 0; pw < PP; ++pw) {
                const size_t o = ((((size_t)b * PP + ph) * PP + pw) * HDIM + y) * WDIM + xg * 4;
                float4 v;
                v.x = acc[pw][0]; v.y = acc[pw][1]; v.z = acc[pw][2]; v.w = acc[pw][3];
                *(float4*)(out + o) = v;
            }
        }
    }
}

extern "C" void kernel_launch(void* const* d_in, const int* in_sizes, int n_in,
                              void* d_out, int out_size, void* d_ws, size_t ws_size,
                              hipStream_t stream) {
    const float* in1 = (const float*)d_in[0];
    const float* in2 = (const float*)d_in[1];
    float* out = (float*)d_out;

    const size_t elems = (size_t)BDIM * HW * CDIM;           // per input
    const size_t need  = 2 * elems * sizeof(unsigned short); // 64 MB
    if (ws_size >= need) {
        unsigned short* t1 = (unsigned short*)d_ws;
        unsigned short* t2 = t1 + elems;
        transpose_bf16_kernel<<<2 * BDIM * 4 * 256, 256, 0, stream>>>(in1, in2, t1, t2);
        hipFuncSetAttribute((const void*)corr_mfma_kernel,
                            hipFuncAttributeMaxDynamicSharedMemorySize, LDS_TOTAL);
        corr_mfma_kernel<<<BDIM * HDIM, 512, LDS_TOTAL, stream>>>(t1, t2, out);
    } else {
        corr_kernel<<<BDIM * HDIM, 256, 0, stream>>>(in1, in2, out);
    }
}